// Round 8
// baseline (392.962 us; speedup 1.0000x reference)
//
#include <hip/hip_runtime.h>
#include <hip/hip_bf16.h>

#define N_NODES 50000
#define N_EDGES 800000
#define N_TOT   850000   // edges + self loops
#define DIM 128
#define HEADS 8
#define CH 16
#define FF 512
#define LN_EPS 1e-5f
#define NEG_SLOPE 0.2f

typedef __bf16 bf16x8 __attribute__((ext_vector_type(8)));
typedef float f32x4 __attribute__((ext_vector_type(4)));

__device__ __forceinline__ float bfr2f(unsigned short u) {
  return __uint_as_float(((unsigned)u) << 16);
}
__device__ __forceinline__ unsigned short f2bfr(float f) {
  __hip_bfloat16 h = __float2bfloat16(f);
  return *(unsigned short*)&h;
}
__device__ __forceinline__ float bf2f(__hip_bfloat16 h) { return __bfloat162float(h); }
__device__ __forceinline__ __hip_bfloat16 f2bf(float f) { return __float2bfloat16(f); }

__device__ __forceinline__ bf16x8 ldcvt8(const float* __restrict__ p) {
  const float4 a = ((const float4*)p)[0];
  const float4 b = ((const float4*)p)[1];
  bf16x8 r;
  r[0] = (__bf16)a.x; r[1] = (__bf16)a.y; r[2] = (__bf16)a.z; r[3] = (__bf16)a.w;
  r[4] = (__bf16)b.x; r[5] = (__bf16)b.y; r[6] = (__bf16)b.z; r[7] = (__bf16)b.w;
  return r;
}
__device__ __forceinline__ void load8f(const float* __restrict__ p, float* v) {
  const float4 a = ((const float4*)p)[0];
  const float4 b = ((const float4*)p)[1];
  v[0]=a.x; v[1]=a.y; v[2]=a.z; v[3]=a.w; v[4]=b.x; v[5]=b.y; v[6]=b.z; v[7]=b.w;
}

__device__ __forceinline__ int ld_src(const int* ei, int mode, int e) {
  int v = mode ? ei[2 * e] : ei[e];
  return min(max(v, 0), N_NODES - 1);
}
__device__ __forceinline__ int ld_dst(const int* ei, int mode, int e) {
  int v = mode ? ei[2 * (N_EDGES + e)] : ei[N_EDGES + e];
  return min(max(v, 0), N_NODES - 1);
}

// ---------------- K0: setup — cvt weights to bf16 + zero deg/fill + mode flag ----
__global__ __launch_bounds__(256) void k_setup(const float* __restrict__ Wg,
                                               const float* __restrict__ W1,
                                               const float* __restrict__ W2,
                                               __hip_bfloat16* __restrict__ wb,
                                               const int* __restrict__ ei,
                                               int* __restrict__ flag,
                                               int* __restrict__ dz) {
  int i = blockIdx.x * 256 + threadIdx.x;
  if (i < 16384)       wb[i] = f2bf(Wg[i]);
  else if (i < 81920)  wb[i] = f2bf(W1[i - 16384]);
  else if (i < 147456) wb[i] = f2bf(W2[i - 81920]);
  if (i < 100096) dz[i] = 0;          // deg + fill (contiguous)
  if (i == 0) {
    int any = 0;
    for (int k = 1; k < 64; k += 2) any |= ei[k];
    *flag = (any == 0) ? 1 : 0;       // 1 = int64 packing
  }
}

// ---------------- K1: xl = bf16( x @ W_gat^T ) -----------------------------------
__global__ __launch_bounds__(256) void k_xl(const float* __restrict__ x,
                                            const __hip_bfloat16* __restrict__ Wgb,
                                            __hip_bfloat16* __restrict__ xl) {
  int w = (blockIdx.x * blockDim.x + threadIdx.x) >> 6;
  if (w >= 3125 * 2) return;
  int l = threadIdx.x & 63, quad = l >> 4, r = l & 15;
  int strip = w >> 1, cc = w & 1;
  const __bf16* wb = (const __bf16*)Wgb;
  f32x4 acc[4];
#pragma unroll
  for (int t = 0; t < 4; ++t) acc[t] = (f32x4){0.f, 0.f, 0.f, 0.f};
  int arow = strip * 16 + r;
  bf16x8 af[4];
#pragma unroll
  for (int kk = 0; kk < 4; ++kk) af[kk] = ldcvt8(x + arow * DIM + kk * 32 + quad * 8);
#pragma unroll
  for (int kk = 0; kk < 4; ++kk) {
    bf16x8 bfr[4];
#pragma unroll
    for (int t = 0; t < 4; ++t)
      bfr[t] = *(const bf16x8*)(wb + (cc * 64 + t * 16 + r) * DIM + kk * 32 + quad * 8);
#pragma unroll
    for (int t = 0; t < 4; ++t)
      acc[t] = __builtin_amdgcn_mfma_f32_16x16x32_bf16(af[kk], bfr[t], acc[t], 0, 0, 0);
  }
#pragma unroll
  for (int t = 0; t < 4; ++t)
#pragma unroll
    for (int j = 0; j < 4; ++j) {
      int row = strip * 16 + quad * 4 + j;
      int col = cc * 64 + t * 16 + r;
      xl[row * DIM + col] = f2bf(acc[t][j]);
    }
}

// ---------------- K2: a_s[n,h], a_d[n,h] (fp32) ----------------------------------
__global__ __launch_bounds__(256) void k_score(const __hip_bfloat16* __restrict__ xl,
                                               const float* __restrict__ att_s,
                                               const float* __restrict__ att_d,
                                               float* __restrict__ a_s, float* __restrict__ a_d) {
  int t = blockIdx.x * 256 + threadIdx.x;
  if (t >= N_NODES * HEADS) return;
  int n = t >> 3, h = t & 7;
  const __hip_bfloat16* p = xl + n * DIM + h * CH;
  float s = 0.f, d = 0.f;
#pragma unroll
  for (int c = 0; c < CH; ++c) {
    float v = bf2f(p[c]);
    s += v * att_s[h * CH + c];
    d += v * att_d[h * CH + c];
  }
  a_s[t] = s; a_d[t] = d;
}

// ---------------- K3: CSR build --------------------------------------------------
__global__ __launch_bounds__(256) void k_hist(const int* __restrict__ ei, const int* __restrict__ flag,
                                              int* __restrict__ deg) {
  int e = blockIdx.x * 256 + threadIdx.x;
  if (e < N_EDGES) atomicAdd(&deg[ld_dst(ei, *flag, e)], 1);
}

// 4 nodes per thread, 13 iterations
__global__ __launch_bounds__(1024) void k_scan(const int* __restrict__ deg, int* __restrict__ offs) {
  __shared__ int wtot[16];
  __shared__ int wbase[16];
  __shared__ int running_s;
  int tid = threadIdx.x, wv = tid >> 6, ln = tid & 63;
  if (tid == 0) running_s = 0;
  __syncthreads();
  for (int base = 0; base < N_NODES; base += 4096) {
    int i0 = base + tid * 4;
    int v0 = 0, v1 = 0, v2 = 0, v3 = 0;
    if (i0 + 3 < N_NODES) {
      int4 dv = *(const int4*)(deg + i0);
      v0 = dv.x + 1; v1 = dv.y + 1; v2 = dv.z + 1; v3 = dv.w + 1;
    } else {
      if (i0 + 0 < N_NODES) v0 = deg[i0 + 0] + 1;
      if (i0 + 1 < N_NODES) v1 = deg[i0 + 1] + 1;
      if (i0 + 2 < N_NODES) v2 = deg[i0 + 2] + 1;
      if (i0 + 3 < N_NODES) v3 = deg[i0 + 3] + 1;
    }
    int tt = v0 + v1 + v2 + v3;
    int xsc = tt;
#pragma unroll
    for (int off = 1; off < 64; off <<= 1) {
      int t = __shfl_up(xsc, off);
      if (ln >= off) xsc += t;
    }
    if (ln == 63) wtot[wv] = xsc;
    __syncthreads();
    if (wv == 0) {
      int t = (ln < 16) ? wtot[ln] : 0;
#pragma unroll
      for (int off = 1; off < 16; off <<= 1) {
        int u = __shfl_up(t, off);
        if (ln >= off) t += u;
      }
      if (ln < 16) wbase[ln] = t;
    }
    __syncthreads();
    int run0 = running_s;
    int excl = run0 + ((wv == 0) ? 0 : wbase[wv - 1]) + xsc - tt;
    if (i0 + 0 < N_NODES) offs[i0 + 0] = excl;
    excl += v0;
    if (i0 + 1 < N_NODES) offs[i0 + 1] = excl;
    excl += v1;
    if (i0 + 2 < N_NODES) offs[i0 + 2] = excl;
    excl += v2;
    if (i0 + 3 < N_NODES) offs[i0 + 3] = excl;
    __syncthreads();
    if (tid == 1023) running_s = run0 + wbase[15];
  }
  __syncthreads();
  if (tid == 0) offs[N_NODES] = running_s;
}

// self-loop slot + edge scatter, fused
__global__ __launch_bounds__(256) void k_scatter(const int* __restrict__ ei, const int* __restrict__ flag,
                                                 const int* __restrict__ offs,
                                                 int* __restrict__ fill, int* __restrict__ eid,
                                                 int* __restrict__ did) {
  int e = blockIdx.x * 256 + threadIdx.x;
  if (e < N_NODES) { int p = offs[e]; eid[p] = e; did[p] = e; }
  if (e < N_EDGES) {
    int m = *flag;
    int d = ld_dst(ei, m, e);
    int p = offs[d] + 1 + atomicAdd(&fill[d], 1);
    eid[p] = ld_src(ei, m, e);
    did[p] = d;
  }
}

// ---------------- K3b: per-edge exp scores (bf16), no max subtraction ------------
__global__ __launch_bounds__(256) void k_escore(const int* __restrict__ eid, const int* __restrict__ did,
                                                const float* __restrict__ a_s, const float* __restrict__ a_d,
                                                unsigned short* __restrict__ ex) {
  int p = blockIdx.x * 256 + threadIdx.x;
  if (p >= N_TOT) return;
  int s = eid[p], d = did[p];
  float as8[8], ad8[8];
  load8f(a_s + s * 8, as8);
  load8f(a_d + d * 8, ad8);
  unsigned int o[4];
#pragma unroll
  for (int k = 0; k < 4; ++k) {
    float v0 = as8[2 * k] + ad8[2 * k];
    v0 = v0 > 0.f ? v0 : NEG_SLOPE * v0;
    float v1 = as8[2 * k + 1] + ad8[2 * k + 1];
    v1 = v1 > 0.f ? v1 : NEG_SLOPE * v1;
    unsigned short e0 = f2bfr(__expf(v0));
    unsigned short e1 = f2bfr(__expf(v1));
    o[k] = (unsigned)e0 | ((unsigned)e1 << 16);
  }
  *(uint4*)(ex + p * 8) = make_uint4(o[0], o[1], o[2], o[3]);
}

// ---------------- K4: per-node aggregation + LN1 ---------------------------------
__global__ __launch_bounds__(256) void k_attn(const int* __restrict__ eid, const int* __restrict__ offs,
                                              const unsigned short* __restrict__ ex,
                                              const __hip_bfloat16* __restrict__ xl,
                                              const float* __restrict__ x,
                                              const float* __restrict__ bias,
                                              const float* __restrict__ g1,
                                              const float* __restrict__ be1,
                                              __hip_bfloat16* __restrict__ h1out) {
  int wv = threadIdx.x >> 6, l = threadIdx.x & 63;
  int n = blockIdx.x * 4 + wv;       // 12500*4 == 50000
  int start = offs[n], end = offs[n + 1];

  // per-head sum of ex, coalesced flat reads (lane l -> head l&7)
  float sme = 0.f;
  int flat1 = end * 8;
  for (int q = start * 8 + l; q < flat1; q += 64) sme += bfr2f(ex[q]);
  sme += __shfl_xor(sme, 8);
  sme += __shfl_xor(sme, 16);
  sme += __shfl_xor(sme, 32);
  float smh = __shfl(sme, l >> 3);
  float inv = 1.f / (smh + 1e-16f);

  // unnormalized aggregation, 4x unroll
  int h = l >> 3;
  const unsigned short* xlu = (const unsigned short*)xl;
  float A0 = 0.f, A1 = 0.f, B0 = 0.f, B1 = 0.f, C0 = 0.f, C1 = 0.f, D0 = 0.f, D1 = 0.f;
  int p = start;
  for (; p + 4 <= end; p += 4) {
    int s0 = eid[p], s1 = eid[p + 1], s2 = eid[p + 2], s3 = eid[p + 3];
    float w0 = bfr2f(ex[(p)     * 8 + h]);
    float w1 = bfr2f(ex[(p + 1) * 8 + h]);
    float w2 = bfr2f(ex[(p + 2) * 8 + h]);
    float w3 = bfr2f(ex[(p + 3) * 8 + h]);
    ushort2 u0 = *(const ushort2*)(xlu + s0 * DIM + 2 * l);
    ushort2 u1 = *(const ushort2*)(xlu + s1 * DIM + 2 * l);
    ushort2 u2 = *(const ushort2*)(xlu + s2 * DIM + 2 * l);
    ushort2 u3 = *(const ushort2*)(xlu + s3 * DIM + 2 * l);
    A0 += w0 * bfr2f(u0.x); A1 += w0 * bfr2f(u0.y);
    B0 += w1 * bfr2f(u1.x); B1 += w1 * bfr2f(u1.y);
    C0 += w2 * bfr2f(u2.x); C1 += w2 * bfr2f(u2.y);
    D0 += w3 * bfr2f(u3.x); D1 += w3 * bfr2f(u3.y);
  }
  for (; p < end; ++p) {
    int s = eid[p];
    float wq = bfr2f(ex[p * 8 + h]);
    ushort2 u = *(const ushort2*)(xlu + s * DIM + 2 * l);
    A0 += wq * bfr2f(u.x); A1 += wq * bfr2f(u.y);
  }
  float acc0 = ((A0 + B0) + (C0 + D0)) * inv;
  float acc1 = ((A1 + B1) + (C1 + D1)) * inv;

  // residual + LayerNorm1
  float2 xv = *(const float2*)(x + n * DIM + 2 * l);
  float2 bv = *(const float2*)(bias + 2 * l);
  float v0 = acc0 + bv.x + xv.x;
  float v1 = acc1 + bv.y + xv.y;
  float s2 = v0 + v1;
  for (int off = 32; off >= 1; off >>= 1) s2 += __shfl_xor(s2, off);
  float mu = s2 * (1.f / 128.f);
  float d0 = v0 - mu, d1 = v1 - mu;
  float q = d0 * d0 + d1 * d1;
  for (int off = 32; off >= 1; off >>= 1) q += __shfl_xor(q, off);
  float rs = rsqrtf(q * (1.f / 128.f) + LN_EPS);
  float2 gv = *(const float2*)(g1 + 2 * l);
  float2 bev = *(const float2*)(be1 + 2 * l);
  ushort2 o;
  o.x = f2bfr(d0 * rs * gv.x + bev.x);
  o.y = f2bfr(d1 * rs * gv.y + bev.y);
  *(ushort2*)((unsigned short*)h1out + n * DIM + 2 * l) = o;
}

// ---------------- K5: fused FFN v4: 512 threads, 8 waves / 32-node tile ----------
// phase 1: wave wv computes hidden f-range [wv*64, wv*64+64) for 32 nodes
//          (acc = 32 regs/wave). waves 0-1 also stage the h1 tile into LDS.
// phase 2: wave wv computes out cols [wv*16, wv*16+16), K=512 from LDS,
//          residual from LDS. Small per-wave state -> high occupancy + short chains.
#define LDSP 520   // hid row pitch (bf16): 16B-aligned, 2-way banks (free)
#define LDSR 136   // h1s row pitch (bf16)
__global__ __launch_bounds__(512) void k_ffn(const __hip_bfloat16* __restrict__ h1,
                                             const __hip_bfloat16* __restrict__ W1b,
                                             const float* __restrict__ b1,
                                             const __hip_bfloat16* __restrict__ W2b,
                                             const float* __restrict__ b2,
                                             const float* __restrict__ g2,
                                             const float* __restrict__ be2,
                                             float* __restrict__ out) {
  __shared__ __bf16 hid[32 * LDSP];          // 33,280 B
  __shared__ __bf16 h1s[32 * LDSR];          // 8,704 B
  __shared__ float ps[8][2][16], pq[8][2][16]; // 8,192 B
  int wv = threadIdx.x >> 6, l = threadIdx.x & 63, quad = l >> 4, r = l & 15;
  int base = blockIdx.x * 32;                // grid 1563; h1 padded to 50016 rows
  const __bf16* h1b = (const __bf16*)h1;
  const __bf16* w1 = (const __bf16*)W1b;
  const __bf16* w2 = (const __bf16*)W2b;

  // ---- phase 1 ----
  bf16x8 bn[2][4];
#pragma unroll
  for (int kk = 0; kk < 4; ++kk) {
    bn[0][kk] = *(const bf16x8*)(h1b + (base + r) * DIM + kk * 32 + quad * 8);
    bn[1][kk] = *(const bf16x8*)(h1b + (base + 16 + r) * DIM + kk * 32 + quad * 8);
  }
  // stage h1 tile into LDS (waves 0,1 -> rows 0-15 / 16-31)
  if (wv < 2) {
#pragma unroll
    for (int kk = 0; kk < 4; ++kk)
      *(bf16x8*)&h1s[(wv * 16 + r) * LDSR + kk * 32 + quad * 8] = bn[wv][kk];
  }
  f32x4 acc1[4][2];
#pragma unroll
  for (int tm = 0; tm < 4; ++tm)
#pragma unroll
    for (int tn = 0; tn < 2; ++tn) acc1[tm][tn] = (f32x4){0.f, 0.f, 0.f, 0.f};
#pragma unroll
  for (int kk = 0; kk < 4; ++kk) {
    bf16x8 wf[4];
#pragma unroll
    for (int tm = 0; tm < 4; ++tm)
      wf[tm] = *(const bf16x8*)(w1 + (wv * 64 + tm * 16 + r) * DIM + kk * 32 + quad * 8);
#pragma unroll
    for (int tm = 0; tm < 4; ++tm) {
      acc1[tm][0] = __builtin_amdgcn_mfma_f32_16x16x32_bf16(wf[tm], bn[0][kk], acc1[tm][0], 0, 0, 0);
      acc1[tm][1] = __builtin_amdgcn_mfma_f32_16x16x32_bf16(wf[tm], bn[1][kk], acc1[tm][1], 0, 0, 0);
    }
  }
  // bias + relu + packed b64 LDS write
#pragma unroll
  for (int tm = 0; tm < 4; ++tm) {
    int f0 = wv * 64 + tm * 16 + quad * 4;
    float4 bb = *(const float4*)(b1 + f0);
#pragma unroll
    for (int tn = 0; tn < 2; ++tn) {
      int node = tn * 16 + r;
      ushort4 o;
      o.x = f2bfr(fmaxf(acc1[tm][tn][0] + bb.x, 0.f));
      o.y = f2bfr(fmaxf(acc1[tm][tn][1] + bb.y, 0.f));
      o.z = f2bfr(fmaxf(acc1[tm][tn][2] + bb.z, 0.f));
      o.w = f2bfr(fmaxf(acc1[tm][tn][3] + bb.w, 0.f));
      *(ushort4*)&hid[node * LDSP + f0] = o;
    }
  }
  __syncthreads();

  // ---- phase 2: out cols [wv*16, wv*16+16), K = 512 from LDS ----
  int col = wv * 16 + r;
  f32x4 acc2[2];
  acc2[0] = (f32x4){0.f, 0.f, 0.f, 0.f};
  acc2[1] = (f32x4){0.f, 0.f, 0.f, 0.f};
#pragma unroll
  for (int kk = 0; kk < 16; ++kk) {
    bf16x8 a0 = *(const bf16x8*)&hid[(r) * LDSP + kk * 32 + quad * 8];
    bf16x8 a1 = *(const bf16x8*)&hid[(16 + r) * LDSP + kk * 32 + quad * 8];
    bf16x8 wq = *(const bf16x8*)(w2 + col * FF + kk * 32 + quad * 8);
    acc2[0] = __builtin_amdgcn_mfma_f32_16x16x32_bf16(a0, wq, acc2[0], 0, 0, 0);
    acc2[1] = __builtin_amdgcn_mfma_f32_16x16x32_bf16(a1, wq, acc2[1], 0, 0, 0);
  }
  // bias + residual (from LDS)
  float b2c = b2[col], g2c = g2[col], be2c = be2[col];
#pragma unroll
  for (int s = 0; s < 2; ++s)
#pragma unroll
    for (int j = 0; j < 4; ++j)
      acc2[s][j] += b2c + bf2f(*(const __hip_bfloat16*)&h1s[(s * 16 + quad * 4 + j) * LDSR + col]);
  // per-row LN moments: wave-local 16-col partials
#pragma unroll
  for (int s = 0; s < 2; ++s)
#pragma unroll
    for (int j = 0; j < 4; ++j) {
      float sm = acc2[s][j];
      float qm = acc2[s][j] * acc2[s][j];
      sm += __shfl_xor(sm, 1); sm += __shfl_xor(sm, 2); sm += __shfl_xor(sm, 4); sm += __shfl_xor(sm, 8);
      qm += __shfl_xor(qm, 1); qm += __shfl_xor(qm, 2); qm += __shfl_xor(qm, 4); qm += __shfl_xor(qm, 8);
      if (r == j) { ps[wv][s][quad * 4 + j] = sm; pq[wv][s][quad * 4 + j] = qm; }
    }
  __syncthreads();
#pragma unroll
  for (int s = 0; s < 2; ++s)
#pragma unroll
    for (int j = 0; j < 4; ++j) {
      int row16 = quad * 4 + j;
      float st = ((ps[0][s][row16] + ps[1][s][row16]) + (ps[2][s][row16] + ps[3][s][row16]))
               + ((ps[4][s][row16] + ps[5][s][row16]) + (ps[6][s][row16] + ps[7][s][row16]));
      float qt = ((pq[0][s][row16] + pq[1][s][row16]) + (pq[2][s][row16] + pq[3][s][row16]))
               + ((pq[4][s][row16] + pq[5][s][row16]) + (pq[6][s][row16] + pq[7][s][row16]));
      float mu = st * (1.f / 128.f);
      float var = qt * (1.f / 128.f) - mu * mu;
      float rs = rsqrtf(var + LN_EPS);
      int grow = base + s * 16 + row16;
      if (grow < N_NODES)
        out[grow * DIM + col] = (acc2[s][j] - mu) * rs * g2c + be2c;
    }
}

// ---------------- workspace layout (bytes, 256-aligned) --------------------------
#define OFF_XL     0u
#define SZ_XL      (N_NODES * DIM * 2u)               // 12,800,000 (bf16)
#define OFF_AS     (OFF_XL + SZ_XL)
#define SZ_AS      (N_NODES * HEADS * 4u)             // 1,600,000
#define OFF_AD     (OFF_AS + SZ_AS)
#define OFF_DEG    (OFF_AD + SZ_AS)
#define SZ_DEG     200192u
#define OFF_FILL   (OFF_DEG + SZ_DEG)
#define OFF_OFFS   (OFF_FILL + SZ_DEG)
#define SZ_OFFS    200448u
#define OFF_FLAG   (OFF_OFFS + SZ_OFFS)
#define OFF_EID    (OFF_FLAG + 256u)
#define SZ_EID     3400192u                           // 850048 * 4
#define OFF_DID    (OFF_EID + SZ_EID)
#define OFF_EX     (OFF_DID + SZ_EID)
#define SZ_EX      13600768u                          // 850048 * 8 * 2 (bf16)
#define OFF_H1     (OFF_EX + SZ_EX)
#define SZ_H1      (50016u * DIM * 2u)                // padded rows for 32-row ffn blocks
#define OFF_WB     (OFF_H1 + SZ_H1)                   // bf16 weights: Wg|W1|W2

extern "C" void kernel_launch(void* const* d_in, const int* in_sizes, int n_in,
                              void* d_out, int out_size, void* d_ws, size_t ws_size,
                              hipStream_t stream) {
  const float* x     = (const float*)d_in[0];
  const int*   ei    = (const int*)d_in[1];
  const float* Wg    = (const float*)d_in[2];
  const float* att_s = (const float*)d_in[3];
  const float* att_d = (const float*)d_in[4];
  const float* bias  = (const float*)d_in[5];
  const float* W1    = (const float*)d_in[6];
  const float* b1    = (const float*)d_in[7];
  const float* W2    = (const float*)d_in[8];
  const float* b2    = (const float*)d_in[9];
  const float* g1    = (const float*)d_in[10];
  const float* be1   = (const float*)d_in[11];
  const float* g2    = (const float*)d_in[12];
  const float* be2   = (const float*)d_in[13];

  char* ws = (char*)d_ws;
  __hip_bfloat16* xl     = (__hip_bfloat16*)(ws + OFF_XL);
  float*          a_s    = (float*)(ws + OFF_AS);
  float*          a_d    = (float*)(ws + OFF_AD);
  int*            deg    = (int*)(ws + OFF_DEG);
  int*            fill   = (int*)(ws + OFF_FILL);
  int*            offs   = (int*)(ws + OFF_OFFS);
  int*            flag   = (int*)(ws + OFF_FLAG);
  int*            eid    = (int*)(ws + OFF_EID);
  int*            did    = (int*)(ws + OFF_DID);
  unsigned short* ex     = (unsigned short*)(ws + OFF_EX);
  __hip_bfloat16* h1     = (__hip_bfloat16*)(ws + OFF_H1);
  __hip_bfloat16* wbuf   = (__hip_bfloat16*)(ws + OFF_WB);
  __hip_bfloat16* Wgb    = wbuf;
  __hip_bfloat16* W1b    = wbuf + 16384;
  __hip_bfloat16* W2b    = wbuf + 81920;
  float*          out    = (float*)d_out;

  k_setup  <<<576,   256, 0, stream>>>(Wg, W1, W2, wbuf, ei, flag, deg);
  k_xl     <<<1563,  256, 0, stream>>>(x, Wgb, xl);
  k_score  <<<1563,  256, 0, stream>>>(xl, att_s, att_d, a_s, a_d);
  k_hist   <<<3125,  256, 0, stream>>>(ei, flag, deg);
  k_scan   <<<1,    1024, 0, stream>>>(deg, offs);
  k_scatter<<<3125,  256, 0, stream>>>(ei, flag, offs, fill, eid, did);
  k_escore <<<3321,  256, 0, stream>>>(eid, did, a_s, a_d, ex);
  k_attn   <<<12500, 256, 0, stream>>>(eid, offs, ex, xl, x, bias, g1, be1, h1);
  k_ffn    <<<1563,  512, 0, stream>>>(h1, W1b, b1, W2b, b2, g2, be2, out);
}